// Round 6
// baseline (191.585 us; speedup 1.0000x reference)
//
#include <hip/hip_runtime.h>

#define SDIM   256
#define VDIM   64
#define VFLAT  192   // VDIM * 3
#define SG4    64    // SDIM / 4
#define VG4    48    // VFLAT / 4
#define BSEG   512
#define NLANES 16    // node-lanes per stats block (1024 threads / 64 lanes)
#define EPS    1e-6f

// normalize kernel geometry
#define NBLK   2048  // blocks
#define NTHR   256   // threads (4 node-lanes of 64)

typedef float nfloat4 __attribute__((ext_vector_type(4)));

__device__ inline void acc4(float4& a, const float4& b) {
    a.x += b.x; a.y += b.y; a.z += b.z; a.w += b.w;
}
__device__ inline void fma4(float4& a, const float4& x) {
    a.x += x.x * x.x; a.y += x.y * x.y; a.z += x.z * x.z; a.w += x.w * x.w;
}
__device__ inline float4 ntload4(const float* p) {
    nfloat4 r = __builtin_nontemporal_load((const nfloat4*)p);
    return make_float4(r.x, r.y, r.z, r.w);
}
__device__ inline void ntstore4(float* p, float4 v) {
    nfloat4 r = {v.x, v.y, v.z, v.w};
    __builtin_nontemporal_store(r, (nfloat4*)p);
}

// ---------------- kernel A: per-segment stats -> workspace ----------------
// One 1024-thread block per segment (batch sorted -> contiguous range).
// Writes per-segment scalar affine (a4,b4 per dim-group) and per-channel
// vector inverse-mean to d_ws.
__global__ __launch_bounds__(1024) void stats_kernel(
    const float* __restrict__ s,
    const float* __restrict__ v,
    const int*   __restrict__ batch,
    const float* __restrict__ weight,
    const float* __restrict__ bias,
    float4* __restrict__ wsA,    // [BSEG][SG4]
    float4* __restrict__ wsB,    // [BSEG][SG4]
    float*  __restrict__ wsV,    // [BSEG][VDIM]
    int n_nodes)
{
    const int b   = blockIdx.x;
    const int tid = threadIdx.x;
    const int g   = tid & 63;
    const int nid = tid >> 6;

    __shared__ int    seg_bounds[2];
    __shared__ float4 red0[NLANES][SG4];
    __shared__ float4 red1[NLANES][SG4];
    __shared__ float  lds_vpf[VFLAT];

    if (tid < 2) {
        const int key = b + tid;
        int lo = 0, hi = n_nodes;
        while (lo < hi) {
            int mid = (lo + hi) >> 1;
            if (batch[mid] < key) lo = mid + 1; else hi = mid;
        }
        seg_bounds[tid] = lo;
    }
    __syncthreads();
    const int lo = seg_bounds[0];
    const int hi = seg_bounds[1];
    const float cnt     = fmaxf((float)(hi - lo), 1.0f);
    const float inv_cnt = 1.0f / cnt;

    const float* srow = s + 4 * g;
    const float* vrow = v + 4 * g;

    float4 ssum4 = {0.f, 0.f, 0.f, 0.f};
    float4 ssq4  = {0.f, 0.f, 0.f, 0.f};
    float4 vp4   = {0.f, 0.f, 0.f, 0.f};
    int n = lo + nid;
    for (; n + 3 * NLANES < hi; n += 4 * NLANES) {
        const int n1 = n + NLANES, n2 = n + 2 * NLANES, n3 = n + 3 * NLANES;
        float4 x0 = *(const float4*)(srow + (size_t)n  * SDIM);
        float4 x1 = *(const float4*)(srow + (size_t)n1 * SDIM);
        float4 x2 = *(const float4*)(srow + (size_t)n2 * SDIM);
        float4 x3 = *(const float4*)(srow + (size_t)n3 * SDIM);
        float4 y0, y1, y2, y3;
        if (g < VG4) {
            y0 = *(const float4*)(vrow + (size_t)n  * VFLAT);
            y1 = *(const float4*)(vrow + (size_t)n1 * VFLAT);
            y2 = *(const float4*)(vrow + (size_t)n2 * VFLAT);
            y3 = *(const float4*)(vrow + (size_t)n3 * VFLAT);
        }
        acc4(ssum4, x0); fma4(ssq4, x0);
        acc4(ssum4, x1); fma4(ssq4, x1);
        acc4(ssum4, x2); fma4(ssq4, x2);
        acc4(ssum4, x3); fma4(ssq4, x3);
        if (g < VG4) { fma4(vp4, y0); fma4(vp4, y1); fma4(vp4, y2); fma4(vp4, y3); }
    }
#pragma clang loop unroll(disable)
    for (; n < hi; n += NLANES) {
        float4 x = *(const float4*)(srow + (size_t)n * SDIM);
        acc4(ssum4, x); fma4(ssq4, x);
        if (g < VG4) {
            float4 y = *(const float4*)(vrow + (size_t)n * VFLAT);
            fma4(vp4, y);
        }
    }

    red0[nid][g] = ssum4;
    red1[nid][g] = ssq4;
    __syncthreads();
    for (int st = NLANES / 2; st >= 1; st >>= 1) {
        if (nid < st) {
            acc4(red0[nid][g], red0[nid + st][g]);
            acc4(red1[nid][g], red1[nid + st][g]);
        }
        __syncthreads();
    }
    if (nid == 0) {
        float4 sum = red0[0][g], sq = red1[0][g];
        float4 w4 = *(const float4*)(weight + 4 * g);
        float4 b4 = *(const float4*)(bias + 4 * g);
        float4 a_, b_;
        {
            float m = sum.x * inv_cnt, var = sq.x * inv_cnt - m * m;
            float p = 1.0f / sqrtf(fmaxf(var, EPS));
            a_.x = p * w4.x; b_.x = b4.x - m * a_.x;
        }
        {
            float m = sum.y * inv_cnt, var = sq.y * inv_cnt - m * m;
            float p = 1.0f / sqrtf(fmaxf(var, EPS));
            a_.y = p * w4.y; b_.y = b4.y - m * a_.y;
        }
        {
            float m = sum.z * inv_cnt, var = sq.z * inv_cnt - m * m;
            float p = 1.0f / sqrtf(fmaxf(var, EPS));
            a_.z = p * w4.z; b_.z = b4.z - m * a_.z;
        }
        {
            float m = sum.w * inv_cnt, var = sq.w * inv_cnt - m * m;
            float p = 1.0f / sqrtf(fmaxf(var, EPS));
            a_.w = p * w4.w; b_.w = b4.w - m * a_.w;
        }
        wsA[b * SG4 + g] = a_;
        wsB[b * SG4 + g] = b_;
    }
    __syncthreads();

    red0[nid][g] = (g < VG4) ? vp4 : make_float4(0.f, 0.f, 0.f, 0.f);
    __syncthreads();
    for (int st = NLANES / 2; st >= 1; st >>= 1) {
        if (nid < st) acc4(red0[nid][g], red0[nid + st][g]);
        __syncthreads();
    }
    if (nid == 0 && g < VG4) {
        float4 t = red0[0][g];
        lds_vpf[4 * g + 0] = t.x;
        lds_vpf[4 * g + 1] = t.y;
        lds_vpf[4 * g + 2] = t.z;
        lds_vpf[4 * g + 3] = t.w;
    }
    __syncthreads();
    if (tid < VDIM) {
        float vm = (lds_vpf[3 * tid] + lds_vpf[3 * tid + 1] + lds_vpf[3 * tid + 2]) * inv_cnt;
        wsV[b * VDIM + tid] = 1.0f / fmaxf(vm, EPS);
    }
}

// ---------------- kernel B: balanced streaming normalize ----------------
// 2048 blocks x 256 threads; block i owns a uniform contiguous node range.
// g = tid & 63 owns dim-group; nid = tid >> 6 strides nodes 4-way.
// Per-wave segment constants cached in registers; reloaded only when the
// (wave-uniform) segment id changes (~once per 24 nodes).
__global__ __launch_bounds__(NTHR) void norm_kernel(
    const float* __restrict__ s,
    const float* __restrict__ v,
    const int*   __restrict__ batch,
    const float4* __restrict__ wsA,
    const float4* __restrict__ wsB,
    const float*  __restrict__ wsV,
    float* __restrict__ sout,
    float* __restrict__ vout,
    int n_nodes, int nodes_per_blk)
{
    const int tid = threadIdx.x;
    const int g   = tid & 63;
    const int nid = tid >> 6;               // 0..3

    const int base = blockIdx.x * nodes_per_blk;
    const int end  = min(base + nodes_per_blk, n_nodes);

    const float* srow = s + 4 * g;
    const float* vrow = v + 4 * g;
    float* so = sout + 4 * g;
    float* vo = vout + 4 * g;

    int cur_seg = -1;
    float4 a4 = {0,0,0,0}, b4 = {0,0,0,0}, vi4 = {0,0,0,0};

    for (int n = base + nid; n < end; n += 4) {
        const int seg = batch[n];            // wave-uniform
        if (seg != cur_seg) {
            cur_seg = seg;
            a4 = wsA[seg * SG4 + g];
            b4 = wsB[seg * SG4 + g];
            if (g < VG4) {
                const float* vv = wsV + seg * VDIM;
                vi4.x = vv[(4 * g + 0) / 3];
                vi4.y = vv[(4 * g + 1) / 3];
                vi4.z = vv[(4 * g + 2) / 3];
                vi4.w = vv[(4 * g + 3) / 3];
            }
        }
        float4 x = ntload4(srow + (size_t)n * SDIM);
        float4 y;
        if (g < VG4) y = ntload4(vrow + (size_t)n * VFLAT);
        float4 o;
        o.x = x.x * a4.x + b4.x; o.y = x.y * a4.y + b4.y;
        o.z = x.z * a4.z + b4.z; o.w = x.w * a4.w + b4.w;
        ntstore4(so + (size_t)n * SDIM, o);
        if (g < VG4) {
            float4 u;
            u.x = y.x * vi4.x; u.y = y.y * vi4.y;
            u.z = y.z * vi4.z; u.w = y.w * vi4.w;
            ntstore4(vo + (size_t)n * VFLAT, u);
        }
    }
}

extern "C" void kernel_launch(void* const* d_in, const int* in_sizes, int n_in,
                              void* d_out, int out_size, void* d_ws, size_t ws_size,
                              hipStream_t stream)
{
    const float* s      = (const float*)d_in[0];
    const float* v      = (const float*)d_in[1];
    const int*   batch  = (const int*)  d_in[2];
    const float* weight = (const float*)d_in[3];
    const float* bias   = (const float*)d_in[4];

    const int n_nodes = in_sizes[2];   // N

    float* sout = (float*)d_out;
    float* vout = sout + (size_t)n_nodes * SDIM;

    float4* wsA = (float4*)d_ws;                 // [BSEG][SG4]  512 KB
    float4* wsB = wsA + (size_t)BSEG * SG4;      // [BSEG][SG4]  512 KB
    float*  wsV = (float*)(wsB + (size_t)BSEG * SG4);  // [BSEG][VDIM] 128 KB

    stats_kernel<<<dim3(BSEG), dim3(1024), 0, stream>>>(
        s, v, batch, weight, bias, wsA, wsB, wsV, n_nodes);

    const int npb = (n_nodes + NBLK - 1) / NBLK;
    norm_kernel<<<dim3(NBLK), dim3(NTHR), 0, stream>>>(
        s, v, batch, wsA, wsB, wsV, sout, vout, n_nodes, npb);
}

// Round 7
// 167.282 us; speedup vs baseline: 1.1453x; 1.1453x over previous
//
#include <hip/hip_runtime.h>

#define SDIM   256
#define VDIM   64
#define VFLAT  192   // VDIM * 3
#define SG4    64    // SDIM / 4 : float4 groups for s
#define VG4    48    // VFLAT / 4: float4 groups for v
#define BSEG   512
#define NLANES 16    // node-lanes per block (1024 threads / 64 dim-groups)
#define EPS    1e-6f

typedef float nfloat4 __attribute__((ext_vector_type(4)));

__device__ inline void acc4(float4& a, const float4& b) {
    a.x += b.x; a.y += b.y; a.z += b.z; a.w += b.w;
}
__device__ inline void fma4(float4& a, const float4& x) {
    a.x += x.x * x.x; a.y += x.y * x.y; a.z += x.z * x.z; a.w += x.w * x.w;
}
__device__ inline float4 ntload4(const float* p) {
    nfloat4 r = __builtin_nontemporal_load((const nfloat4*)p);
    return make_float4(r.x, r.y, r.z, r.w);
}
__device__ inline void ntstore4(float* p, float4 v) {
    nfloat4 r = {v.x, v.y, v.z, v.w};
    __builtin_nontemporal_store(r, (nfloat4*)p);
}

// One block (1024 threads) per segment; batch[] sorted -> contiguous range.
// g = tid & 63 owns float4 dim-group; nid = tid >> 6 strides nodes 16-way.
// Phase 1: unroll-x4 stat accumulation, LDS tree reduce across node-lanes.
// Phase 2: unroll-x4 normalize; nontemporal loads (last use) + nontemporal
//          stores (never re-read). Fused structure keeps phase-2 re-reads
//          temporally close to phase-1 reads -> LLC-served (FETCH ~ 1x input).
__global__ __launch_bounds__(1024) void segnorm_kernel(
    const float* __restrict__ s,
    const float* __restrict__ v,
    const int*   __restrict__ batch,
    const float* __restrict__ weight,
    const float* __restrict__ bias,
    float* __restrict__ sout,
    float* __restrict__ vout,
    int n_nodes)
{
    const int b   = blockIdx.x;
    const int tid = threadIdx.x;
    const int g   = tid & 63;    // dim-group (lane)
    const int nid = tid >> 6;    // node-lane (wave)

    __shared__ int    seg_bounds[2];
    __shared__ float4 red0[NLANES][SG4];
    __shared__ float4 red1[NLANES][SG4];
    __shared__ float4 lds_a[SG4];
    __shared__ float4 lds_b[SG4];
    __shared__ float  lds_vpf[VFLAT];
    __shared__ float  lds_vinv[VDIM];

    if (tid < 2) {
        const int key = b + tid;
        int lo = 0, hi = n_nodes;
        while (lo < hi) {
            int mid = (lo + hi) >> 1;
            if (batch[mid] < key) lo = mid + 1; else hi = mid;
        }
        seg_bounds[tid] = lo;
    }
    __syncthreads();
    const int lo = seg_bounds[0];
    const int hi = seg_bounds[1];
    const float cnt     = fmaxf((float)(hi - lo), 1.0f);
    const float inv_cnt = 1.0f / cnt;

    const float* srow = s + 4 * g;
    const float* vrow = v + 4 * g;

    // ---------- phase 1: stats (unroll x4: 8 loads in flight) ----------
    float4 ssum4 = {0.f, 0.f, 0.f, 0.f};
    float4 ssq4  = {0.f, 0.f, 0.f, 0.f};
    float4 vp4   = {0.f, 0.f, 0.f, 0.f};
    int n = lo + nid;
    for (; n + 3 * NLANES < hi; n += 4 * NLANES) {
        const int n1 = n + NLANES, n2 = n + 2 * NLANES, n3 = n + 3 * NLANES;
        float4 x0 = *(const float4*)(srow + (size_t)n  * SDIM);
        float4 x1 = *(const float4*)(srow + (size_t)n1 * SDIM);
        float4 x2 = *(const float4*)(srow + (size_t)n2 * SDIM);
        float4 x3 = *(const float4*)(srow + (size_t)n3 * SDIM);
        float4 y0, y1, y2, y3;
        if (g < VG4) {
            y0 = *(const float4*)(vrow + (size_t)n  * VFLAT);
            y1 = *(const float4*)(vrow + (size_t)n1 * VFLAT);
            y2 = *(const float4*)(vrow + (size_t)n2 * VFLAT);
            y3 = *(const float4*)(vrow + (size_t)n3 * VFLAT);
        }
        acc4(ssum4, x0); fma4(ssq4, x0);
        acc4(ssum4, x1); fma4(ssq4, x1);
        acc4(ssum4, x2); fma4(ssq4, x2);
        acc4(ssum4, x3); fma4(ssq4, x3);
        if (g < VG4) { fma4(vp4, y0); fma4(vp4, y1); fma4(vp4, y2); fma4(vp4, y3); }
    }
#pragma clang loop unroll(disable)
    for (; n < hi; n += NLANES) {
        float4 x = *(const float4*)(srow + (size_t)n * SDIM);
        acc4(ssum4, x); fma4(ssq4, x);
        if (g < VG4) {
            float4 y = *(const float4*)(vrow + (size_t)n * VFLAT);
            fma4(vp4, y);
        }
    }

    // reduce ssum/ssq across the 16 node-lanes
    red0[nid][g] = ssum4;
    red1[nid][g] = ssq4;
    __syncthreads();
    for (int st = NLANES / 2; st >= 1; st >>= 1) {
        if (nid < st) {
            acc4(red0[nid][g], red0[nid + st][g]);
            acc4(red1[nid][g], red1[nid + st][g]);
        }
        __syncthreads();
    }
    if (nid == 0) {
        float4 sum = red0[0][g], sq = red1[0][g];
        float4 w4 = *(const float4*)(weight + 4 * g);
        float4 b4 = *(const float4*)(bias + 4 * g);
        float4 a_, b_;
        {
            float m = sum.x * inv_cnt, var = sq.x * inv_cnt - m * m;
            float p = 1.0f / sqrtf(fmaxf(var, EPS));
            a_.x = p * w4.x; b_.x = b4.x - m * a_.x;
        }
        {
            float m = sum.y * inv_cnt, var = sq.y * inv_cnt - m * m;
            float p = 1.0f / sqrtf(fmaxf(var, EPS));
            a_.y = p * w4.y; b_.y = b4.y - m * a_.y;
        }
        {
            float m = sum.z * inv_cnt, var = sq.z * inv_cnt - m * m;
            float p = 1.0f / sqrtf(fmaxf(var, EPS));
            a_.z = p * w4.z; b_.z = b4.z - m * a_.z;
        }
        {
            float m = sum.w * inv_cnt, var = sq.w * inv_cnt - m * m;
            float p = 1.0f / sqrtf(fmaxf(var, EPS));
            a_.w = p * w4.w; b_.w = b4.w - m * a_.w;
        }
        lds_a[g] = a_;
        lds_b[g] = b_;
    }
    __syncthreads();

    // reduce vp across node-lanes (reuse red0)
    red0[nid][g] = (g < VG4) ? vp4 : make_float4(0.f, 0.f, 0.f, 0.f);
    __syncthreads();
    for (int st = NLANES / 2; st >= 1; st >>= 1) {
        if (nid < st) acc4(red0[nid][g], red0[nid + st][g]);
        __syncthreads();
    }
    if (nid == 0 && g < VG4) {
        float4 t = red0[0][g];
        lds_vpf[4 * g + 0] = t.x;
        lds_vpf[4 * g + 1] = t.y;
        lds_vpf[4 * g + 2] = t.z;
        lds_vpf[4 * g + 3] = t.w;
    }
    __syncthreads();
    if (tid < VDIM) {
        float vm = (lds_vpf[3 * tid] + lds_vpf[3 * tid + 1] + lds_vpf[3 * tid + 2]) * inv_cnt;
        lds_vinv[tid] = 1.0f / fmaxf(vm, EPS);
    }
    __syncthreads();

    const float4 a4 = lds_a[g];
    const float4 b4 = lds_b[g];
    float4 vi4 = {0.f, 0.f, 0.f, 0.f};
    if (g < VG4) {
        vi4.x = lds_vinv[(4 * g + 0) / 3];
        vi4.y = lds_vinv[(4 * g + 1) / 3];
        vi4.z = lds_vinv[(4 * g + 2) / 3];
        vi4.w = lds_vinv[(4 * g + 3) / 3];
    }

    float* so = sout + 4 * g;
    float* vo = vout + 4 * g;

    // ---------- phase 2: normalize + write (unroll x4, nt loads/stores) ----------
    n = lo + nid;
    for (; n + 3 * NLANES < hi; n += 4 * NLANES) {
        const int n1 = n + NLANES, n2 = n + 2 * NLANES, n3 = n + 3 * NLANES;
        float4 x0 = ntload4(srow + (size_t)n  * SDIM);
        float4 x1 = ntload4(srow + (size_t)n1 * SDIM);
        float4 x2 = ntload4(srow + (size_t)n2 * SDIM);
        float4 x3 = ntload4(srow + (size_t)n3 * SDIM);
        float4 y0, y1, y2, y3;
        if (g < VG4) {
            y0 = ntload4(vrow + (size_t)n  * VFLAT);
            y1 = ntload4(vrow + (size_t)n1 * VFLAT);
            y2 = ntload4(vrow + (size_t)n2 * VFLAT);
            y3 = ntload4(vrow + (size_t)n3 * VFLAT);
        }
        float4 o;
        o.x = x0.x * a4.x + b4.x; o.y = x0.y * a4.y + b4.y;
        o.z = x0.z * a4.z + b4.z; o.w = x0.w * a4.w + b4.w;
        ntstore4(so + (size_t)n  * SDIM, o);
        o.x = x1.x * a4.x + b4.x; o.y = x1.y * a4.y + b4.y;
        o.z = x1.z * a4.z + b4.z; o.w = x1.w * a4.w + b4.w;
        ntstore4(so + (size_t)n1 * SDIM, o);
        o.x = x2.x * a4.x + b4.x; o.y = x2.y * a4.y + b4.y;
        o.z = x2.z * a4.z + b4.z; o.w = x2.w * a4.w + b4.w;
        ntstore4(so + (size_t)n2 * SDIM, o);
        o.x = x3.x * a4.x + b4.x; o.y = x3.y * a4.y + b4.y;
        o.z = x3.z * a4.z + b4.z; o.w = x3.w * a4.w + b4.w;
        ntstore4(so + (size_t)n3 * SDIM, o);
        if (g < VG4) {
            float4 u;
            u.x = y0.x * vi4.x; u.y = y0.y * vi4.y;
            u.z = y0.z * vi4.z; u.w = y0.w * vi4.w;
            ntstore4(vo + (size_t)n  * VFLAT, u);
            u.x = y1.x * vi4.x; u.y = y1.y * vi4.y;
            u.z = y1.z * vi4.z; u.w = y1.w * vi4.w;
            ntstore4(vo + (size_t)n1 * VFLAT, u);
            u.x = y2.x * vi4.x; u.y = y2.y * vi4.y;
            u.z = y2.z * vi4.z; u.w = y2.w * vi4.w;
            ntstore4(vo + (size_t)n2 * VFLAT, u);
            u.x = y3.x * vi4.x; u.y = y3.y * vi4.y;
            u.z = y3.z * vi4.z; u.w = y3.w * vi4.w;
            ntstore4(vo + (size_t)n3 * VFLAT, u);
        }
    }
#pragma clang loop unroll(disable)
    for (; n < hi; n += NLANES) {
        float4 x = ntload4(srow + (size_t)n * SDIM);
        float4 o;
        o.x = x.x * a4.x + b4.x; o.y = x.y * a4.y + b4.y;
        o.z = x.z * a4.z + b4.z; o.w = x.w * a4.w + b4.w;
        ntstore4(so + (size_t)n * SDIM, o);
        if (g < VG4) {
            float4 y = ntload4(vrow + (size_t)n * VFLAT);
            float4 u;
            u.x = y.x * vi4.x; u.y = y.y * vi4.y;
            u.z = y.z * vi4.z; u.w = y.w * vi4.w;
            ntstore4(vo + (size_t)n * VFLAT, u);
        }
    }
}

extern "C" void kernel_launch(void* const* d_in, const int* in_sizes, int n_in,
                              void* d_out, int out_size, void* d_ws, size_t ws_size,
                              hipStream_t stream)
{
    const float* s      = (const float*)d_in[0];
    const float* v      = (const float*)d_in[1];
    const int*   batch  = (const int*)  d_in[2];
    const float* weight = (const float*)d_in[3];
    const float* bias   = (const float*)d_in[4];

    const int n_nodes = in_sizes[2];   // N

    float* sout = (float*)d_out;
    float* vout = sout + (size_t)n_nodes * SDIM;

    segnorm_kernel<<<dim3(BSEG), dim3(1024), 0, stream>>>(
        s, v, batch, weight, bias, sout, vout, n_nodes);
}